// Round 2
// baseline (277.594 us; speedup 1.0000x reference)
//
#include <hip/hip_runtime.h>
#include <math.h>

#define DIMN 1536
#define NHEAD 12
#define HDIM 128
#define SLEN 2048
#define EPSV 1e-6f

typedef __attribute__((ext_vector_type(8))) short short8;
typedef __attribute__((ext_vector_type(4))) short short4v;
typedef __attribute__((ext_vector_type(4))) float f32x4;

typedef __attribute__((address_space(1))) const void gvoid_t;
typedef __attribute__((address_space(3))) void lvoid_t;

__device__ __forceinline__ void gload_lds16(const void* g, void* l) {
    __builtin_amdgcn_global_load_lds((gvoid_t*)g, (lvoid_t*)l, 16, 0, 0);
}

__device__ inline short to_bf16(float f) {
    union { float f; unsigned u; } v; v.f = f;
    unsigned r = (v.u + 0x7FFFu + ((v.u >> 16) & 1u)) >> 16;
    return (short)r;
}
__device__ inline float bf_to_f(short h) {
    union { unsigned u; float f; } v;
    v.u = ((unsigned)(unsigned short)h) << 16;
    return v.f;
}

// 8-chunk XOR swizzle for the GEMM LDS tiles.
__device__ __forceinline__ int swz8(int row, int c) {
    return c ^ (row & 7);
}

// ---------------------------------------------------------------------------
// Cast 5 fp32 tensors to bf16 (x + 4 weights), one launch.
// ---------------------------------------------------------------------------
__global__ __launch_bounds__(256)
void cast5(const float* s0, const float* s1, const float* s2,
           const float* s3, const float* s4,
           short* d0, short* d1, short* d2, short* d3, short* d4,
           int n0, int nw)
{
    const float* s; short* d; int n;
    switch (blockIdx.y) {
        case 0: s = s0; d = d0; n = n0; break;
        case 1: s = s1; d = d1; n = nw; break;
        case 2: s = s2; d = d2; n = nw; break;
        case 3: s = s3; d = d3; n = nw; break;
        default: s = s4; d = d4; n = nw; break;
    }
    int idx = (blockIdx.x * 256 + threadIdx.x) * 8;
    if (idx >= n) return;
    float4 a = *(const float4*)(s + idx);
    float4 b = *(const float4*)(s + idx + 4);
    short8 r;
    r[0] = to_bf16(a.x); r[1] = to_bf16(a.y); r[2] = to_bf16(a.z); r[3] = to_bf16(a.w);
    r[4] = to_bf16(b.x); r[5] = to_bf16(b.y); r[6] = to_bf16(b.z); r[7] = to_bf16(b.w);
    *(short8*)(d + idx) = r;
}

// ---------------------------------------------------------------------------
// BK=64 MFMA GEMM core (unchanged).
// ---------------------------------------------------------------------------
__device__ __forceinline__ void gemm_mainloop(const short* __restrict__ A,
    const short* __restrict__ W, int m0, int n0, int K,
    short* As, short* Bs, f32x4 (&acc)[4][4])
{
    const int tid = threadIdx.x;
    const int wave = tid >> 6, lane = tid & 63;
    const int quad = lane >> 4, col = lane & 15;
    const int wm = wave >> 1, wn = wave & 1;
    const int sr = tid >> 3;
    const int sc = tid & 7;

    for (int kt = 0; kt < K; kt += 64) {
        __syncthreads();
        #pragma unroll
        for (int i = 0; i < 4; ++i) {
            const int row = i * 32 + sr;
            const int c = swz8(row, sc);
            gload_lds16(A + (size_t)(m0 + row) * K + kt + c * 8, As + i * 2048 + tid * 8);
        }
        #pragma unroll
        for (int i = 0; i < 4; ++i) {
            const int row = i * 32 + sr;
            const int c = swz8(row, sc);
            gload_lds16(W + (size_t)(n0 + row) * K + kt + c * 8, Bs + i * 2048 + tid * 8);
        }
        __syncthreads();

        #pragma unroll
        for (int kb = 0; kb < 2; ++kb) {
            short8 af[4], bf[4];
            #pragma unroll
            for (int mt = 0; mt < 4; ++mt) {
                const int row = wm * 64 + mt * 16 + col;
                af[mt] = *(const short8*)&As[row * 64 + swz8(row, kb * 4 + quad) * 8];
            }
            #pragma unroll
            for (int nt = 0; nt < 4; ++nt) {
                const int row = wn * 64 + nt * 16 + col;
                bf[nt] = *(const short8*)&Bs[row * 64 + swz8(row, kb * 4 + quad) * 8];
            }
            #pragma unroll
            for (int mt = 0; mt < 4; ++mt)
                #pragma unroll
                for (int nt = 0; nt < 4; ++nt)
                    acc[mt][nt] = __builtin_amdgcn_mfma_f32_16x16x32_bf16(
                        af[mt], bf[nt], acc[mt][nt], 0, 0, 0);
        }
    }
}

// ---------------------------------------------------------------------------
// Fused QKV GEMM; sel==2 (V) writes fragment-swizzled Vp directly.
// Vp chunks are 32-key-step-major: chunk = (head*64 + step)*8 + dt, so each
// step's V tile is 8 KB contiguous and fragment-ready.
// ---------------------------------------------------------------------------
__global__ __launch_bounds__(256)
void gemm_qkv(const short* __restrict__ A,
              const short* __restrict__ W0, const short* __restrict__ W1,
              const short* __restrict__ W2,
              const float* __restrict__ b0, const float* __restrict__ b1,
              const float* __restrict__ b2,
              short* __restrict__ Y0, short* __restrict__ Y1,
              short* __restrict__ Vp)
{
    __shared__ __attribute__((aligned(16))) short As[128 * 64];
    __shared__ __attribute__((aligned(16))) short Bs[128 * 64];

    const int sel = blockIdx.x / (DIMN / 128);
    const int nb  = blockIdx.x % (DIMN / 128);
    const short* W    = (sel == 0) ? W0 : (sel == 1) ? W1 : W2;
    const float* bias = (sel == 0) ? b0 : (sel == 1) ? b1 : b2;

    const int tid = threadIdx.x;
    const int wave = tid >> 6, lane = tid & 63;
    const int quad = lane >> 4, col = lane & 15;
    const int wm = wave >> 1, wn = wave & 1;
    const int m0 = blockIdx.y * 128, n0 = nb * 128;

    f32x4 acc[4][4];
    #pragma unroll
    for (int i = 0; i < 4; ++i)
        #pragma unroll
        for (int j = 0; j < 4; ++j)
            #pragma unroll
            for (int r = 0; r < 4; ++r) acc[i][j][r] = 0.f;

    gemm_mainloop(A, W, m0, n0, DIMN, As, Bs, acc);

    if (sel < 2) {
        short* Y = (sel == 0) ? Y0 : Y1;
        #pragma unroll
        for (int mt = 0; mt < 4; ++mt) {
            #pragma unroll
            for (int nt = 0; nt < 4; ++nt) {
                const int n = n0 + wn * 64 + nt * 16 + col;
                const float bb = bias[n];
                #pragma unroll
                for (int r = 0; r < 4; ++r) {
                    const int m = m0 + wm * 64 + mt * 16 + quad * 4 + r;
                    Y[(size_t)m * DIMN + n] = to_bf16(acc[mt][nt][r] + bb);
                }
            }
        }
    } else {
        const int head = nb;
        const int kt64 = blockIdx.y * 2 + wm;
        #pragma unroll
        for (int mt = 0; mt < 4; ++mt) {
            #pragma unroll
            for (int nt = 0; nt < 4; ++nt) {
                const int n = n0 + wn * 64 + nt * 16 + col;
                const float bb = bias[n];
                const int dt = wn * 4 + nt;
                // 32-key step index = kt64*2 + (mt>>1); 8 dt-chunks contiguous.
                const int chunk = (head * 64 + kt64 * 2 + (mt >> 1)) * 8 + dt;
                const int off = ((mt & 1) * 2 + (quad >> 1)) * 128 + col * 8 + (quad & 1) * 4;
                short4v o;
                #pragma unroll
                for (int r = 0; r < 4; ++r) o[r] = to_bf16(acc[mt][nt][r] + bb);
                *(short4v*)(Vp + (size_t)chunk * 512 + off) = o;
            }
        }
    }
}

// ---------------------------------------------------------------------------
// Output-projection GEMM, fp32 out.
// ---------------------------------------------------------------------------
__global__ __launch_bounds__(256)
void gemm_out(const short* __restrict__ A, const short* __restrict__ W,
              const float* __restrict__ bias, float* __restrict__ Yf)
{
    __shared__ __attribute__((aligned(16))) short As[128 * 64];
    __shared__ __attribute__((aligned(16))) short Bs[128 * 64];

    const int tid = threadIdx.x;
    const int wave = tid >> 6, lane = tid & 63;
    const int quad = lane >> 4, col = lane & 15;
    const int wm = wave >> 1, wn = wave & 1;
    const int m0 = blockIdx.y * 128, n0 = blockIdx.x * 128;

    f32x4 acc[4][4];
    #pragma unroll
    for (int i = 0; i < 4; ++i)
        #pragma unroll
        for (int j = 0; j < 4; ++j)
            #pragma unroll
            for (int r = 0; r < 4; ++r) acc[i][j][r] = 0.f;

    gemm_mainloop(A, W, m0, n0, DIMN, As, Bs, acc);

    #pragma unroll
    for (int mt = 0; mt < 4; ++mt) {
        #pragma unroll
        for (int nt = 0; nt < 4; ++nt) {
            const int n = n0 + wn * 64 + nt * 16 + col;
            const float bb = bias[n];
            #pragma unroll
            for (int r = 0; r < 4; ++r) {
                const int m = m0 + wm * 64 + mt * 16 + quad * 4 + r;
                Yf[(size_t)m * DIMN + n] = acc[mt][nt][r] + bb;
            }
        }
    }
}

// ---------------------------------------------------------------------------
// Fused RMSNorm + RoPE for Q (grid.y==0, in-place) and K->Kp (grid.y==1).
// ---------------------------------------------------------------------------
__global__ __launch_bounds__(256)
void rms_rope_qk(short* __restrict__ qbuf, const short* __restrict__ kbuf,
                 short* __restrict__ Kp,
                 const float* __restrict__ gq, const float* __restrict__ gk,
                 const float* __restrict__ freqs, const int* __restrict__ grid_sizes)
{
    const int s = blockIdx.x;
    const int isK = blockIdx.y;
    const int tid = threadIdx.x;
    short* qrow = qbuf + (size_t)s * DIMN;
    const short* row = isK ? (kbuf + (size_t)s * DIMN) : qrow;
    const float* g = isK ? gk : gq;

    float ss = 0.f;
    if (tid < 192) {
        short8 v = *(const short8*)(row + tid * 8);
        #pragma unroll
        for (int j = 0; j < 8; ++j) { float f = bf_to_f(v[j]); ss += f * f; }
    }
    #pragma unroll
    for (int off = 32; off; off >>= 1) ss += __shfl_down(ss, off, 64);

    __shared__ float red[4];
    __shared__ float s_scale;
    if ((tid & 63) == 0) red[tid >> 6] = ss;
    __syncthreads();
    if (tid == 0) {
        float t = red[0] + red[1] + red[2] + red[3];
        float sc = rsqrtf(t / (float)DIMN + EPSV);
        s_scale = isK ? sc : sc * 0.08838834764831845f;
    }
    __syncthreads();
    const float scale = s_scale;

    const int h = grid_sizes[1], w = grid_sizes[2];
    const int fi = s / (h * w);
    const int hi = (s / w) % h;
    const int wi = s % w;

    if (!isK) {
        for (int p = tid; p < NHEAD * 64; p += 256) {
            const int n = p >> 6;
            const int d = p & 63;
            const int idx = (d < 22) ? fi : ((d < 43) ? hi : wi);
            const float ang = freqs[idx * 64 + d];
            float sn, cs;
            __sincosf(ang, &sn, &cs);
            const int base = n * HDIM + 2 * d;
            const float v0 = bf_to_f(qrow[base]) * scale * g[base];
            const float v1 = bf_to_f(qrow[base + 1]) * scale * g[base + 1];
            qrow[base]     = to_bf16(v0 * cs - v1 * sn);
            qrow[base + 1] = to_bf16(v0 * sn + v1 * cs);
        }
    } else if (tid < 192) {
        const int n = tid >> 4;
        const int o = tid & 15;
        short8 outv;
        #pragma unroll
        for (int pp = 0; pp < 4; ++pp) {
            const int pd = o * 4 + pp;
            const int idx = (pd < 22) ? fi : ((pd < 43) ? hi : wi);
            const float ang = freqs[idx * 64 + pd];
            float sn, cs;
            __sincosf(ang, &sn, &cs);
            const int base = n * HDIM + 2 * pd;
            const float v0 = bf_to_f(row[base]) * scale * g[base];
            const float v1 = bf_to_f(row[base + 1]) * scale * g[base + 1];
            outv[pp * 2]     = to_bf16(v0 * cs - v1 * sn);
            outv[pp * 2 + 1] = to_bf16(v0 * sn + v1 * cs);
        }
        const int kb = s >> 4, colk = s & 15;
        const int kc = o >> 2, quadk = o & 3;
        const size_t addr = ((((size_t)(n * 128 + kb) * 4 + kc) * 64) + quadk * 16 + colk) * 8;
        *(short8*)(Kp + addr) = outv;
    }
}

// ---------------------------------------------------------------------------
// MFMA flash attention v8 — LDS-free, barrier-free register streaming.
//
// Diagnosis: v6/v7 were LDS-BW-bound (~3.2 GB LDS traffic: 34 KB frag reads
// + 16 KB stage writes per block-step; ~46 us at the 69 TB/s LDS ceiling).
// With 2-wave blocks nothing in LDS was truly shared per-wave, so LDS
// staging was pure overhead.
//
// v8: one wave (64 thr) per block owns 32 q-rows (2 row-frags). K/V
// fragments are read DIRECTLY global->VGPR (same L2 traffic as staging,
// zero LDS), double-buffered in registers so the compiler emits counted
// vmcnt waits (register prefetch pipelining works at source level).
// No __syncthreads anywhere. LDS use: 2.5 KB P-transpose buffer only
// (wave-private, stride-40 padded, 16B-aligned b128 reads).
// ~280 VGPR; __launch_bounds__(64,1) allows up to 512, no spill.
// Grid 768 one-wave blocks = 3/CU balanced. XCD swizzle clusters each
// head's K/V (1 MB) on 1-2 XCDs so the 12 MB working set fits per-XCD L2.
// ---------------------------------------------------------------------------
__global__ __launch_bounds__(64, 1)
void attn_mfma8(const short* __restrict__ Q, const short* __restrict__ Kp,
                const short* __restrict__ Vp, short* __restrict__ O,
                const int* __restrict__ seq_lens)
{
    __shared__ __attribute__((aligned(16))) short psw[2 * 16 * 40];  // 2.5 KB

    const int lane = threadIdx.x;          // 64-thread block = 1 wave
    const int quad = lane >> 4, col = lane & 15;

    // XCD-clustering swizzle: hw dispatch order -> head-major chunks of 96,
    // so each XCD's resident blocks touch ~1.5 heads (~1.5 MB K/V) of L2.
    const int orig = blockIdx.y * 64 + blockIdx.x;   // 0..767, hw-linear
    const int work = (orig & 7) * 96 + (orig >> 3);  // bijective (768 % 8 == 0)
    const int head = work >> 6;
    const int row0 = (work & 63) * 32;
    const int slen = seq_lens[0];

    // Q fragments: 2 row-tiles x 4 k-chunks.
    short8 qf[2][4];
    #pragma unroll
    for (int T = 0; T < 2; ++T)
        #pragma unroll
        for (int kc = 0; kc < 4; ++kc)
            qf[T][kc] = *(const short8*)(Q + (size_t)(row0 + T * 16 + col) * DIMN
                                         + head * HDIM + kc * 32 + quad * 8);

    f32x4 oacc[2][8];
    #pragma unroll
    for (int T = 0; T < 2; ++T)
        #pragma unroll
        for (int dt = 0; dt < 8; ++dt)
            #pragma unroll
            for (int r = 0; r < 4; ++r) oacc[T][dt][r] = 0.f;
    float lsum[2][4];
    #pragma unroll
    for (int T = 0; T < 2; ++T)
        #pragma unroll
        for (int r = 0; r < 4; ++r) lsum[T][r] = 0.f;

    // Per-head fragment-ready K/V: 64 steps x 4096 shorts (8 KB).
    const short* kbase = Kp + (size_t)head * 262144 + lane * 8;
    const short* vbase = Vp + (size_t)head * 262144 + lane * 8;

    auto loadKV = [&](short8 (&kf)[8], short8 (&vf)[8], int step) {
        const short* ks = kbase + (size_t)step * 4096;
        const short* vs = vbase + (size_t)step * 4096;
        #pragma unroll
        for (int c = 0; c < 8; ++c) kf[c] = *(const short8*)(ks + c * 512);
        #pragma unroll
        for (int c = 0; c < 8; ++c) vf[c] = *(const short8*)(vs + c * 512);
    };

    auto compute = [&](short8 (&kf)[8], short8 (&vf)[8], int kt) {
        // ---- S = Q K^T: 2 row-tiles x 32 keys ----
        f32x4 s[2][2];
        #pragma unroll
        for (int T = 0; T < 2; ++T)
            #pragma unroll
            for (int nt = 0; nt < 2; ++nt)
                #pragma unroll
                for (int r = 0; r < 4; ++r) s[T][nt][r] = 0.f;

        #pragma unroll
        for (int kc = 0; kc < 4; ++kc)
            #pragma unroll
            for (int T = 0; T < 2; ++T) {
                s[T][0] = __builtin_amdgcn_mfma_f32_16x16x32_bf16(qf[T][kc], kf[kc],     s[T][0], 0, 0, 0);
                s[T][1] = __builtin_amdgcn_mfma_f32_16x16x32_bf16(qf[T][kc], kf[4 + kc], s[T][1], 0, 0, 0);
            }

        // ---- mask + exp (max-free) + l accum + P transpose via tiny LDS ----
        const int kt0 = kt * 32;
        #pragma unroll
        for (int T = 0; T < 2; ++T)
            #pragma unroll
            for (int nt = 0; nt < 2; ++nt) {
                const bool masked = (kt0 + nt * 16 + col >= slen);
                #pragma unroll
                for (int r = 0; r < 4; ++r) {
                    float p = masked ? 0.f : __expf(s[T][nt][r]);
                    lsum[T][r] += p;
                    psw[T * 640 + (quad * 4 + r) * 40 + nt * 16 + col] = to_bf16(p);
                }
            }

        short8 pf0 = *(const short8*)&psw[col * 40 + quad * 8];
        short8 pf1 = *(const short8*)&psw[640 + col * 40 + quad * 8];

        // ---- PV: 8 d-tiles x 2 row-tiles ----
        #pragma unroll
        for (int dt = 0; dt < 8; ++dt) {
            oacc[0][dt] = __builtin_amdgcn_mfma_f32_16x16x32_bf16(pf0, vf[dt], oacc[0][dt], 0, 0, 0);
            oacc[1][dt] = __builtin_amdgcn_mfma_f32_16x16x32_bf16(pf1, vf[dt], oacc[1][dt], 0, 0, 0);
        }
    };

    short8 kA[8], vA[8], kB[8], vB[8];
    loadKV(kA, vA, 0);

    #pragma unroll 1
    for (int kt = 0; kt < SLEN / 32; kt += 2) {
        loadKV(kB, vB, kt + 1);      // prefetch next step into B
        compute(kA, vA, kt);
        loadKV(kA, vA, kt + 2);      // prefetch kt+2 into A (last iter reads
                                     // 8 KB past this head's region -- still
                                     // inside the workspace, value unused)
        compute(kB, vB, kt + 1);
    }

    // ---- epilogue: reduce l over the 16 key-columns, normalize, store ----
    #pragma unroll
    for (int T = 0; T < 2; ++T)
        #pragma unroll
        for (int r = 0; r < 4; ++r) {
            #pragma unroll
            for (int off = 8; off; off >>= 1)
                lsum[T][r] += __shfl_xor(lsum[T][r], off, 64);
            lsum[T][r] = 1.0f / lsum[T][r];
        }

    #pragma unroll
    for (int T = 0; T < 2; ++T)
        #pragma unroll
        for (int dt = 0; dt < 8; ++dt)
            #pragma unroll
            for (int r = 0; r < 4; ++r)
                O[(size_t)(row0 + T * 16 + quad * 4 + r) * DIMN
                  + head * HDIM + dt * 16 + col] = to_bf16(oacc[T][dt][r] * lsum[T][r]);
}

// ---------------------------------------------------------------------------
extern "C" void kernel_launch(void* const* d_in, const int* in_sizes, int n_in,
                              void* d_out, int out_size, void* d_ws, size_t ws_size,
                              hipStream_t stream)
{
    const float* x     = (const float*)d_in[0];
    const float* freqs = (const float*)d_in[1];
    const float* wq    = (const float*)d_in[2];
    const float* bq    = (const float*)d_in[3];
    const float* wk    = (const float*)d_in[4];
    const float* bk    = (const float*)d_in[5];
    const float* wv    = (const float*)d_in[6];
    const float* bv    = (const float*)d_in[7];
    const float* wo    = (const float*)d_in[8];
    const float* bo    = (const float*)d_in[9];
    const float* gq    = (const float*)d_in[10];
    const float* gk    = (const float*)d_in[11];
    const int* seq_lens   = (const int*)d_in[12];
    const int* grid_sizes = (const int*)d_in[13];
    float* out = (float*)d_out;

    const size_t NX = (size_t)SLEN * DIMN;
    const size_t NW = (size_t)DIMN * DIMN;
    short* xb  = (short*)d_ws;
    short* wqb = xb + NX;
    short* wkb = wqb + NW;
    short* wvb = wkb + NW;
    short* wob = wvb + NW;
    short* qb  = wob + NW;
    short* kb  = qb + NX;
    short* vp  = kb + NX;
    short* kp  = vp + NX;
    short* ob  = kp + NX;

    cast5<<<dim3(1536, 5), 256, 0, stream>>>(x, wq, wk, wv, wo,
                                             xb, wqb, wkb, wvb, wob,
                                             (int)NX, (int)NW);

    gemm_qkv<<<dim3(3 * DIMN / 128, SLEN / 128), 256, 0, stream>>>(
        xb, wqb, wkb, wvb, bq, bk, bv, qb, kb, vp);

    rms_rope_qk<<<dim3(SLEN, 2), 256, 0, stream>>>(qb, kb, kp, gq, gk, freqs, grid_sizes);

    attn_mfma8<<<dim3(64, NHEAD), 64, 0, stream>>>(qb, kp, vp, ob, seq_lens);

    gemm_out<<<dim3(DIMN / 128, SLEN / 128), 256, 0, stream>>>(ob, wob, bo, out);
}

// Round 3
// 270.468 us; speedup vs baseline: 1.0264x; 1.0264x over previous
//
#include <hip/hip_runtime.h>
#include <math.h>

#define DIMN 1536
#define NHEAD 12
#define HDIM 128
#define SLEN 2048
#define EPSV 1e-6f

typedef __attribute__((ext_vector_type(8))) short short8;
typedef __attribute__((ext_vector_type(4))) short short4v;
typedef __attribute__((ext_vector_type(4))) float f32x4;

typedef __attribute__((address_space(1))) const void gvoid_t;
typedef __attribute__((address_space(3))) void lvoid_t;

__device__ __forceinline__ void gload_lds16(const void* g, void* l) {
    __builtin_amdgcn_global_load_lds((gvoid_t*)g, (lvoid_t*)l, 16, 0, 0);
}

__device__ inline short to_bf16(float f) {
    union { float f; unsigned u; } v; v.f = f;
    unsigned r = (v.u + 0x7FFFu + ((v.u >> 16) & 1u)) >> 16;
    return (short)r;
}
__device__ inline float bf_to_f(short h) {
    union { unsigned u; float f; } v;
    v.u = ((unsigned)(unsigned short)h) << 16;
    return v.f;
}

// 8-chunk XOR swizzle for the GEMM LDS tiles.
__device__ __forceinline__ int swz8(int row, int c) {
    return c ^ (row & 7);
}

// ---------------------------------------------------------------------------
// Cast 5 fp32 tensors to bf16 (x + 4 weights), one launch.
// ---------------------------------------------------------------------------
__global__ __launch_bounds__(256)
void cast5(const float* s0, const float* s1, const float* s2,
           const float* s3, const float* s4,
           short* d0, short* d1, short* d2, short* d3, short* d4,
           int n0, int nw)
{
    const float* s; short* d; int n;
    switch (blockIdx.y) {
        case 0: s = s0; d = d0; n = n0; break;
        case 1: s = s1; d = d1; n = nw; break;
        case 2: s = s2; d = d2; n = nw; break;
        case 3: s = s3; d = d3; n = nw; break;
        default: s = s4; d = d4; n = nw; break;
    }
    int idx = (blockIdx.x * 256 + threadIdx.x) * 8;
    if (idx >= n) return;
    float4 a = *(const float4*)(s + idx);
    float4 b = *(const float4*)(s + idx + 4);
    short8 r;
    r[0] = to_bf16(a.x); r[1] = to_bf16(a.y); r[2] = to_bf16(a.z); r[3] = to_bf16(a.w);
    r[4] = to_bf16(b.x); r[5] = to_bf16(b.y); r[6] = to_bf16(b.z); r[7] = to_bf16(b.w);
    *(short8*)(d + idx) = r;
}

// ---------------------------------------------------------------------------
// BK=64 MFMA GEMM core (unchanged).
// ---------------------------------------------------------------------------
__device__ __forceinline__ void gemm_mainloop(const short* __restrict__ A,
    const short* __restrict__ W, int m0, int n0, int K,
    short* As, short* Bs, f32x4 (&acc)[4][4])
{
    const int tid = threadIdx.x;
    const int wave = tid >> 6, lane = tid & 63;
    const int quad = lane >> 4, col = lane & 15;
    const int wm = wave >> 1, wn = wave & 1;
    const int sr = tid >> 3;
    const int sc = tid & 7;

    for (int kt = 0; kt < K; kt += 64) {
        __syncthreads();
        #pragma unroll
        for (int i = 0; i < 4; ++i) {
            const int row = i * 32 + sr;
            const int c = swz8(row, sc);
            gload_lds16(A + (size_t)(m0 + row) * K + kt + c * 8, As + i * 2048 + tid * 8);
        }
        #pragma unroll
        for (int i = 0; i < 4; ++i) {
            const int row = i * 32 + sr;
            const int c = swz8(row, sc);
            gload_lds16(W + (size_t)(n0 + row) * K + kt + c * 8, Bs + i * 2048 + tid * 8);
        }
        __syncthreads();

        #pragma unroll
        for (int kb = 0; kb < 2; ++kb) {
            short8 af[4], bf[4];
            #pragma unroll
            for (int mt = 0; mt < 4; ++mt) {
                const int row = wm * 64 + mt * 16 + col;
                af[mt] = *(const short8*)&As[row * 64 + swz8(row, kb * 4 + quad) * 8];
            }
            #pragma unroll
            for (int nt = 0; nt < 4; ++nt) {
                const int row = wn * 64 + nt * 16 + col;
                bf[nt] = *(const short8*)&Bs[row * 64 + swz8(row, kb * 4 + quad) * 8];
            }
            #pragma unroll
            for (int mt = 0; mt < 4; ++mt)
                #pragma unroll
                for (int nt = 0; nt < 4; ++nt)
                    acc[mt][nt] = __builtin_amdgcn_mfma_f32_16x16x32_bf16(
                        af[mt], bf[nt], acc[mt][nt], 0, 0, 0);
        }
    }
}

// ---------------------------------------------------------------------------
// Fused QKV GEMM; sel==2 (V) writes fragment-swizzled Vp directly.
// Vp chunks are 32-key-step-major: chunk = (head*64 + step)*8 + dt, so each
// step's V tile is 8 KB contiguous and fragment-ready.
// ---------------------------------------------------------------------------
__global__ __launch_bounds__(256)
void gemm_qkv(const short* __restrict__ A,
              const short* __restrict__ W0, const short* __restrict__ W1,
              const short* __restrict__ W2,
              const float* __restrict__ b0, const float* __restrict__ b1,
              const float* __restrict__ b2,
              short* __restrict__ Y0, short* __restrict__ Y1,
              short* __restrict__ Vp)
{
    __shared__ __attribute__((aligned(16))) short As[128 * 64];
    __shared__ __attribute__((aligned(16))) short Bs[128 * 64];

    const int sel = blockIdx.x / (DIMN / 128);
    const int nb  = blockIdx.x % (DIMN / 128);
    const short* W    = (sel == 0) ? W0 : (sel == 1) ? W1 : W2;
    const float* bias = (sel == 0) ? b0 : (sel == 1) ? b1 : b2;

    const int tid = threadIdx.x;
    const int wave = tid >> 6, lane = tid & 63;
    const int quad = lane >> 4, col = lane & 15;
    const int wm = wave >> 1, wn = wave & 1;
    const int m0 = blockIdx.y * 128, n0 = nb * 128;

    f32x4 acc[4][4];
    #pragma unroll
    for (int i = 0; i < 4; ++i)
        #pragma unroll
        for (int j = 0; j < 4; ++j)
            #pragma unroll
            for (int r = 0; r < 4; ++r) acc[i][j][r] = 0.f;

    gemm_mainloop(A, W, m0, n0, DIMN, As, Bs, acc);

    if (sel < 2) {
        short* Y = (sel == 0) ? Y0 : Y1;
        #pragma unroll
        for (int mt = 0; mt < 4; ++mt) {
            #pragma unroll
            for (int nt = 0; nt < 4; ++nt) {
                const int n = n0 + wn * 64 + nt * 16 + col;
                const float bb = bias[n];
                #pragma unroll
                for (int r = 0; r < 4; ++r) {
                    const int m = m0 + wm * 64 + mt * 16 + quad * 4 + r;
                    Y[(size_t)m * DIMN + n] = to_bf16(acc[mt][nt][r] + bb);
                }
            }
        }
    } else {
        const int head = nb;
        const int kt64 = blockIdx.y * 2 + wm;
        #pragma unroll
        for (int mt = 0; mt < 4; ++mt) {
            #pragma unroll
            for (int nt = 0; nt < 4; ++nt) {
                const int n = n0 + wn * 64 + nt * 16 + col;
                const float bb = bias[n];
                const int dt = wn * 4 + nt;
                // 32-key step index = kt64*2 + (mt>>1); 8 dt-chunks contiguous.
                const int chunk = (head * 64 + kt64 * 2 + (mt >> 1)) * 8 + dt;
                const int off = ((mt & 1) * 2 + (quad >> 1)) * 128 + col * 8 + (quad & 1) * 4;
                short4v o;
                #pragma unroll
                for (int r = 0; r < 4; ++r) o[r] = to_bf16(acc[mt][nt][r] + bb);
                *(short4v*)(Vp + (size_t)chunk * 512 + off) = o;
            }
        }
    }
}

// ---------------------------------------------------------------------------
// Output-projection GEMM, fp32 out.
// ---------------------------------------------------------------------------
__global__ __launch_bounds__(256)
void gemm_out(const short* __restrict__ A, const short* __restrict__ W,
              const float* __restrict__ bias, float* __restrict__ Yf)
{
    __shared__ __attribute__((aligned(16))) short As[128 * 64];
    __shared__ __attribute__((aligned(16))) short Bs[128 * 64];

    const int tid = threadIdx.x;
    const int wave = tid >> 6, lane = tid & 63;
    const int quad = lane >> 4, col = lane & 15;
    const int wm = wave >> 1, wn = wave & 1;
    const int m0 = blockIdx.y * 128, n0 = blockIdx.x * 128;

    f32x4 acc[4][4];
    #pragma unroll
    for (int i = 0; i < 4; ++i)
        #pragma unroll
        for (int j = 0; j < 4; ++j)
            #pragma unroll
            for (int r = 0; r < 4; ++r) acc[i][j][r] = 0.f;

    gemm_mainloop(A, W, m0, n0, DIMN, As, Bs, acc);

    #pragma unroll
    for (int mt = 0; mt < 4; ++mt) {
        #pragma unroll
        for (int nt = 0; nt < 4; ++nt) {
            const int n = n0 + wn * 64 + nt * 16 + col;
            const float bb = bias[n];
            #pragma unroll
            for (int r = 0; r < 4; ++r) {
                const int m = m0 + wm * 64 + mt * 16 + quad * 4 + r;
                Yf[(size_t)m * DIMN + n] = acc[mt][nt][r] + bb;
            }
        }
    }
}

// ---------------------------------------------------------------------------
// Fused RMSNorm + RoPE for Q (grid.y==0, in-place) and K->Kp (grid.y==1).
// ---------------------------------------------------------------------------
__global__ __launch_bounds__(256)
void rms_rope_qk(short* __restrict__ qbuf, const short* __restrict__ kbuf,
                 short* __restrict__ Kp,
                 const float* __restrict__ gq, const float* __restrict__ gk,
                 const float* __restrict__ freqs, const int* __restrict__ grid_sizes)
{
    const int s = blockIdx.x;
    const int isK = blockIdx.y;
    const int tid = threadIdx.x;
    short* qrow = qbuf + (size_t)s * DIMN;
    const short* row = isK ? (kbuf + (size_t)s * DIMN) : qrow;
    const float* g = isK ? gk : gq;

    float ss = 0.f;
    if (tid < 192) {
        short8 v = *(const short8*)(row + tid * 8);
        #pragma unroll
        for (int j = 0; j < 8; ++j) { float f = bf_to_f(v[j]); ss += f * f; }
    }
    #pragma unroll
    for (int off = 32; off; off >>= 1) ss += __shfl_down(ss, off, 64);

    __shared__ float red[4];
    __shared__ float s_scale;
    if ((tid & 63) == 0) red[tid >> 6] = ss;
    __syncthreads();
    if (tid == 0) {
        float t = red[0] + red[1] + red[2] + red[3];
        float sc = rsqrtf(t / (float)DIMN + EPSV);
        s_scale = isK ? sc : sc * 0.08838834764831845f;
    }
    __syncthreads();
    const float scale = s_scale;

    const int h = grid_sizes[1], w = grid_sizes[2];
    const int fi = s / (h * w);
    const int hi = (s / w) % h;
    const int wi = s % w;

    if (!isK) {
        for (int p = tid; p < NHEAD * 64; p += 256) {
            const int n = p >> 6;
            const int d = p & 63;
            const int idx = (d < 22) ? fi : ((d < 43) ? hi : wi);
            const float ang = freqs[idx * 64 + d];
            float sn, cs;
            __sincosf(ang, &sn, &cs);
            const int base = n * HDIM + 2 * d;
            const float v0 = bf_to_f(qrow[base]) * scale * g[base];
            const float v1 = bf_to_f(qrow[base + 1]) * scale * g[base + 1];
            qrow[base]     = to_bf16(v0 * cs - v1 * sn);
            qrow[base + 1] = to_bf16(v0 * sn + v1 * cs);
        }
    } else if (tid < 192) {
        const int n = tid >> 4;
        const int o = tid & 15;
        short8 outv;
        #pragma unroll
        for (int pp = 0; pp < 4; ++pp) {
            const int pd = o * 4 + pp;
            const int idx = (pd < 22) ? fi : ((pd < 43) ? hi : wi);
            const float ang = freqs[idx * 64 + pd];
            float sn, cs;
            __sincosf(ang, &sn, &cs);
            const int base = n * HDIM + 2 * pd;
            const float v0 = bf_to_f(row[base]) * scale * g[base];
            const float v1 = bf_to_f(row[base + 1]) * scale * g[base + 1];
            outv[pp * 2]     = to_bf16(v0 * cs - v1 * sn);
            outv[pp * 2 + 1] = to_bf16(v0 * sn + v1 * cs);
        }
        const int kb = s >> 4, colk = s & 15;
        const int kc = o >> 2, quadk = o & 3;
        const size_t addr = ((((size_t)(n * 128 + kb) * 4 + kc) * 64) + quadk * 16 + colk) * 8;
        *(short8*)(Kp + addr) = outv;
    }
}

// ---------------------------------------------------------------------------
// MFMA flash attention v9 — split-K register streaming for 4x TLP.
//
// Post-mortem history: v6 (LDS staged, drain), v7 (pipelined vmcnt), v8
// (register streaming, no LDS, no barriers) ALL land at ~70 us with
// MfmaUtil ~14%. Invariant across them: <=1.5 waves/SIMD. The limit is the
// per-wave serial chain (load ~300-900 cyc -> QK 4-dep MFMA -> exp ->
// LDS P round-trip -> PV) x 64 steps with no other wave to fill the
// stalls (v8: 0.75 waves/SIMD, ~2580 cyc/step vs ~250 cyc of issue work).
//
// v9: each wave owns 16 q-rows x 1024 keys (half the key range). 2-wave
// blocks pair the two key-halves of a tile and combine (oacc, lsum)
// through LDS at the end. 128 tiles x 12 heads = 1536 blocks = 3072 waves
// = 12 waves/CU = 3 waves/SIMD (4x v8). VGPR ~150 (single-buffer K/V,
// 1 row-tile) -> __launch_bounds__(128,3) holds 3/SIMD. K loads issue
// before V loads so QK^T overlaps V arrival.
// ---------------------------------------------------------------------------
__global__ __launch_bounds__(128, 3)
void attn_mfma9(const short* __restrict__ Q, const short* __restrict__ Kp,
                const short* __restrict__ Vp, short* __restrict__ O,
                const int* __restrict__ seq_lens)
{
    __shared__ __attribute__((aligned(16))) short psw[2 * 16 * 40]; // P transpose, per wave
    __shared__ __attribute__((aligned(16))) float sacc[16 * 132];   // combine: 16 rows x 128d
    __shared__ float sl[16];                                        // combine: row sums

    const int tid  = threadIdx.x;
    const int wave = tid >> 6;           // 0: keys 0..1023, 1: keys 1024..2047
    const int lane = tid & 63;
    const int quad = lane >> 4, col = lane & 15;

    // XCD-clustering swizzle: 1536 blocks -> 8 chunks of 192 (1.5 heads of
    // K/V ~ 1.5 MB per XCD L2). Bijective since 1536 % 8 == 0.
    const int orig = blockIdx.y * 128 + blockIdx.x;
    const int work = (orig & 7) * 192 + (orig >> 3);
    const int head = work >> 7;
    const int row0 = (work & 127) * 16;
    const int slen = seq_lens[0];

    // Q fragments: 1 row-tile x 4 k-chunks.
    short8 qf[4];
    #pragma unroll
    for (int kc = 0; kc < 4; ++kc)
        qf[kc] = *(const short8*)(Q + (size_t)(row0 + col) * DIMN
                                  + head * HDIM + kc * 32 + quad * 8);

    f32x4 oacc[8];
    #pragma unroll
    for (int dt = 0; dt < 8; ++dt)
        #pragma unroll
        for (int r = 0; r < 4; ++r) oacc[dt][r] = 0.f;
    float lsum[4] = {0.f, 0.f, 0.f, 0.f};

    const short* kbase = Kp + (size_t)head * 262144 + lane * 8;
    const short* vbase = Vp + (size_t)head * 262144 + lane * 8;
    short* pswm = psw + wave * 640;

    const int step0 = wave * 32;
    #pragma unroll 1
    for (int kt = 0; kt < 32; ++kt) {
        const int step = step0 + kt;
        const short* ks = kbase + (size_t)step * 4096;
        const short* vs = vbase + (size_t)step * 4096;

        short8 kf[8], vf[8];
        #pragma unroll
        for (int c = 0; c < 8; ++c) kf[c] = *(const short8*)(ks + c * 512);
        #pragma unroll
        for (int c = 0; c < 8; ++c) vf[c] = *(const short8*)(vs + c * 512);

        // ---- S = Q K^T: 16 rows x 32 keys ----
        f32x4 s[2];
        #pragma unroll
        for (int nt = 0; nt < 2; ++nt)
            #pragma unroll
            for (int r = 0; r < 4; ++r) s[nt][r] = 0.f;

        #pragma unroll
        for (int kc = 0; kc < 4; ++kc) {
            s[0] = __builtin_amdgcn_mfma_f32_16x16x32_bf16(qf[kc], kf[kc],     s[0], 0, 0, 0);
            s[1] = __builtin_amdgcn_mfma_f32_16x16x32_bf16(qf[kc], kf[4 + kc], s[1], 0, 0, 0);
        }

        // ---- mask + exp (max-free) + l accum + P transpose via tiny LDS ----
        const int kt0 = step * 32;
        #pragma unroll
        for (int nt = 0; nt < 2; ++nt) {
            const bool masked = (kt0 + nt * 16 + col >= slen);
            #pragma unroll
            for (int r = 0; r < 4; ++r) {
                float p = masked ? 0.f : __expf(s[nt][r]);
                lsum[r] += p;
                pswm[(quad * 4 + r) * 40 + nt * 16 + col] = to_bf16(p);
            }
        }

        short8 pf = *(const short8*)&pswm[col * 40 + quad * 8];

        // ---- PV: 8 d-tiles ----
        #pragma unroll
        for (int dt = 0; dt < 8; ++dt)
            oacc[dt] = __builtin_amdgcn_mfma_f32_16x16x32_bf16(pf, vf[dt], oacc[dt], 0, 0, 0);
    }

    // ---- reduce l over the 16 key-columns (within 16-lane groups) ----
    #pragma unroll
    for (int r = 0; r < 4; ++r) {
        #pragma unroll
        for (int off = 8; off; off >>= 1)
            lsum[r] += __shfl_xor(lsum[r], off, 64);
    }

    // ---- combine the two key-halves through LDS ----
    if (wave == 1) {
        #pragma unroll
        for (int dt = 0; dt < 8; ++dt)
            #pragma unroll
            for (int r = 0; r < 4; ++r)
                sacc[(quad * 4 + r) * 132 + dt * 16 + col] = oacc[dt][r];
        if (col == 0) {
            #pragma unroll
            for (int r = 0; r < 4; ++r) sl[quad * 4 + r] = lsum[r];
        }
    }
    __syncthreads();
    if (wave == 0) {
        float inv[4];
        #pragma unroll
        for (int r = 0; r < 4; ++r)
            inv[r] = 1.0f / (lsum[r] + sl[quad * 4 + r]);
        #pragma unroll
        for (int dt = 0; dt < 8; ++dt)
            #pragma unroll
            for (int r = 0; r < 4; ++r) {
                const float o = oacc[dt][r] + sacc[(quad * 4 + r) * 132 + dt * 16 + col];
                O[(size_t)(row0 + quad * 4 + r) * DIMN + head * HDIM + dt * 16 + col]
                    = to_bf16(o * inv[r]);
            }
    }
}

// ---------------------------------------------------------------------------
extern "C" void kernel_launch(void* const* d_in, const int* in_sizes, int n_in,
                              void* d_out, int out_size, void* d_ws, size_t ws_size,
                              hipStream_t stream)
{
    const float* x     = (const float*)d_in[0];
    const float* freqs = (const float*)d_in[1];
    const float* wq    = (const float*)d_in[2];
    const float* bq    = (const float*)d_in[3];
    const float* wk    = (const float*)d_in[4];
    const float* bk    = (const float*)d_in[5];
    const float* wv    = (const float*)d_in[6];
    const float* bv    = (const float*)d_in[7];
    const float* wo    = (const float*)d_in[8];
    const float* bo    = (const float*)d_in[9];
    const float* gq    = (const float*)d_in[10];
    const float* gk    = (const float*)d_in[11];
    const int* seq_lens   = (const int*)d_in[12];
    const int* grid_sizes = (const int*)d_in[13];
    float* out = (float*)d_out;

    const size_t NX = (size_t)SLEN * DIMN;
    const size_t NW = (size_t)DIMN * DIMN;
    short* xb  = (short*)d_ws;
    short* wqb = xb + NX;
    short* wkb = wqb + NW;
    short* wvb = wkb + NW;
    short* wob = wvb + NW;
    short* qb  = wob + NW;
    short* kb  = qb + NX;
    short* vp  = kb + NX;
    short* kp  = vp + NX;
    short* ob  = kp + NX;

    cast5<<<dim3(1536, 5), 256, 0, stream>>>(x, wq, wk, wv, wo,
                                             xb, wqb, wkb, wvb, wob,
                                             (int)NX, (int)NW);

    gemm_qkv<<<dim3(3 * DIMN / 128, SLEN / 128), 256, 0, stream>>>(
        xb, wqb, wkb, wvb, bq, bk, bv, qb, kb, vp);

    rms_rope_qk<<<dim3(SLEN, 2), 256, 0, stream>>>(qb, kb, kp, gq, gk, freqs, grid_sizes);

    attn_mfma9<<<dim3(128, NHEAD), 128, 0, stream>>>(qb, kp, vp, ob, seq_lens);

    gemm_out<<<dim3(DIMN / 128, SLEN / 128), 256, 0, stream>>>(ob, wob, bo, out);
}

// Round 4
// 268.673 us; speedup vs baseline: 1.0332x; 1.0067x over previous
//
#include <hip/hip_runtime.h>
#include <math.h>

#define DIMN 1536
#define NHEAD 12
#define HDIM 128
#define SLEN 2048
#define EPSV 1e-6f

typedef __attribute__((ext_vector_type(8))) short short8;
typedef __attribute__((ext_vector_type(4))) short short4v;
typedef __attribute__((ext_vector_type(4))) float f32x4;

typedef __attribute__((address_space(1))) const void gvoid_t;
typedef __attribute__((address_space(3))) void lvoid_t;

__device__ __forceinline__ void gload_lds16(const void* g, void* l) {
    __builtin_amdgcn_global_load_lds((gvoid_t*)g, (lvoid_t*)l, 16, 0, 0);
}

__device__ inline short to_bf16(float f) {
    union { float f; unsigned u; } v; v.f = f;
    unsigned r = (v.u + 0x7FFFu + ((v.u >> 16) & 1u)) >> 16;
    return (short)r;
}
__device__ inline float bf_to_f(short h) {
    union { unsigned u; float f; } v;
    v.u = ((unsigned)(unsigned short)h) << 16;
    return v.f;
}

// 8-chunk XOR swizzle for the GEMM LDS tiles.
__device__ __forceinline__ int swz8(int row, int c) {
    return c ^ (row & 7);
}

// ---------------------------------------------------------------------------
// Cast 5 fp32 tensors to bf16 (x + 4 weights), one launch.
// ---------------------------------------------------------------------------
__global__ __launch_bounds__(256)
void cast5(const float* s0, const float* s1, const float* s2,
           const float* s3, const float* s4,
           short* d0, short* d1, short* d2, short* d3, short* d4,
           int n0, int nw)
{
    const float* s; short* d; int n;
    switch (blockIdx.y) {
        case 0: s = s0; d = d0; n = n0; break;
        case 1: s = s1; d = d1; n = nw; break;
        case 2: s = s2; d = d2; n = nw; break;
        case 3: s = s3; d = d3; n = nw; break;
        default: s = s4; d = d4; n = nw; break;
    }
    int idx = (blockIdx.x * 256 + threadIdx.x) * 8;
    if (idx >= n) return;
    float4 a = *(const float4*)(s + idx);
    float4 b = *(const float4*)(s + idx + 4);
    short8 r;
    r[0] = to_bf16(a.x); r[1] = to_bf16(a.y); r[2] = to_bf16(a.z); r[3] = to_bf16(a.w);
    r[4] = to_bf16(b.x); r[5] = to_bf16(b.y); r[6] = to_bf16(b.z); r[7] = to_bf16(b.w);
    *(short8*)(d + idx) = r;
}

// ---------------------------------------------------------------------------
// BK=64 MFMA GEMM core (unchanged).
// ---------------------------------------------------------------------------
__device__ __forceinline__ void gemm_mainloop(const short* __restrict__ A,
    const short* __restrict__ W, int m0, int n0, int K,
    short* As, short* Bs, f32x4 (&acc)[4][4])
{
    const int tid = threadIdx.x;
    const int wave = tid >> 6, lane = tid & 63;
    const int quad = lane >> 4, col = lane & 15;
    const int wm = wave >> 1, wn = wave & 1;
    const int sr = tid >> 3;
    const int sc = tid & 7;

    for (int kt = 0; kt < K; kt += 64) {
        __syncthreads();
        #pragma unroll
        for (int i = 0; i < 4; ++i) {
            const int row = i * 32 + sr;
            const int c = swz8(row, sc);
            gload_lds16(A + (size_t)(m0 + row) * K + kt + c * 8, As + i * 2048 + tid * 8);
        }
        #pragma unroll
        for (int i = 0; i < 4; ++i) {
            const int row = i * 32 + sr;
            const int c = swz8(row, sc);
            gload_lds16(W + (size_t)(n0 + row) * K + kt + c * 8, Bs + i * 2048 + tid * 8);
        }
        __syncthreads();

        #pragma unroll
        for (int kb = 0; kb < 2; ++kb) {
            short8 af[4], bf[4];
            #pragma unroll
            for (int mt = 0; mt < 4; ++mt) {
                const int row = wm * 64 + mt * 16 + col;
                af[mt] = *(const short8*)&As[row * 64 + swz8(row, kb * 4 + quad) * 8];
            }
            #pragma unroll
            for (int nt = 0; nt < 4; ++nt) {
                const int row = wn * 64 + nt * 16 + col;
                bf[nt] = *(const short8*)&Bs[row * 64 + swz8(row, kb * 4 + quad) * 8];
            }
            #pragma unroll
            for (int mt = 0; mt < 4; ++mt)
                #pragma unroll
                for (int nt = 0; nt < 4; ++nt)
                    acc[mt][nt] = __builtin_amdgcn_mfma_f32_16x16x32_bf16(
                        af[mt], bf[nt], acc[mt][nt], 0, 0, 0);
        }
    }
}

// ---------------------------------------------------------------------------
// Fused QKV GEMM; sel==2 (V) writes fragment-swizzled Vp directly.
// Vp chunks are 32-key-step-major: chunk = (head*64 + step)*8 + dt, so each
// step's V tile is 8 KB contiguous and fragment-ready.
// ---------------------------------------------------------------------------
__global__ __launch_bounds__(256)
void gemm_qkv(const short* __restrict__ A,
              const short* __restrict__ W0, const short* __restrict__ W1,
              const short* __restrict__ W2,
              const float* __restrict__ b0, const float* __restrict__ b1,
              const float* __restrict__ b2,
              short* __restrict__ Y0, short* __restrict__ Y1,
              short* __restrict__ Vp)
{
    __shared__ __attribute__((aligned(16))) short As[128 * 64];
    __shared__ __attribute__((aligned(16))) short Bs[128 * 64];

    const int sel = blockIdx.x / (DIMN / 128);
    const int nb  = blockIdx.x % (DIMN / 128);
    const short* W    = (sel == 0) ? W0 : (sel == 1) ? W1 : W2;
    const float* bias = (sel == 0) ? b0 : (sel == 1) ? b1 : b2;

    const int tid = threadIdx.x;
    const int wave = tid >> 6, lane = tid & 63;
    const int quad = lane >> 4, col = lane & 15;
    const int wm = wave >> 1, wn = wave & 1;
    const int m0 = blockIdx.y * 128, n0 = nb * 128;

    f32x4 acc[4][4];
    #pragma unroll
    for (int i = 0; i < 4; ++i)
        #pragma unroll
        for (int j = 0; j < 4; ++j)
            #pragma unroll
            for (int r = 0; r < 4; ++r) acc[i][j][r] = 0.f;

    gemm_mainloop(A, W, m0, n0, DIMN, As, Bs, acc);

    if (sel < 2) {
        short* Y = (sel == 0) ? Y0 : Y1;
        #pragma unroll
        for (int mt = 0; mt < 4; ++mt) {
            #pragma unroll
            for (int nt = 0; nt < 4; ++nt) {
                const int n = n0 + wn * 64 + nt * 16 + col;
                const float bb = bias[n];
                #pragma unroll
                for (int r = 0; r < 4; ++r) {
                    const int m = m0 + wm * 64 + mt * 16 + quad * 4 + r;
                    Y[(size_t)m * DIMN + n] = to_bf16(acc[mt][nt][r] + bb);
                }
            }
        }
    } else {
        const int head = nb;
        const int kt64 = blockIdx.y * 2 + wm;
        #pragma unroll
        for (int mt = 0; mt < 4; ++mt) {
            #pragma unroll
            for (int nt = 0; nt < 4; ++nt) {
                const int n = n0 + wn * 64 + nt * 16 + col;
                const float bb = bias[n];
                const int dt = wn * 4 + nt;
                // 32-key step index = kt64*2 + (mt>>1); 8 dt-chunks contiguous.
                const int chunk = (head * 64 + kt64 * 2 + (mt >> 1)) * 8 + dt;
                const int off = ((mt & 1) * 2 + (quad >> 1)) * 128 + col * 8 + (quad & 1) * 4;
                short4v o;
                #pragma unroll
                for (int r = 0; r < 4; ++r) o[r] = to_bf16(acc[mt][nt][r] + bb);
                *(short4v*)(Vp + (size_t)chunk * 512 + off) = o;
            }
        }
    }
}

// ---------------------------------------------------------------------------
// Output-projection GEMM, fp32 out.
// ---------------------------------------------------------------------------
__global__ __launch_bounds__(256)
void gemm_out(const short* __restrict__ A, const short* __restrict__ W,
              const float* __restrict__ bias, float* __restrict__ Yf)
{
    __shared__ __attribute__((aligned(16))) short As[128 * 64];
    __shared__ __attribute__((aligned(16))) short Bs[128 * 64];

    const int tid = threadIdx.x;
    const int wave = tid >> 6, lane = tid & 63;
    const int quad = lane >> 4, col = lane & 15;
    const int wm = wave >> 1, wn = wave & 1;
    const int m0 = blockIdx.y * 128, n0 = blockIdx.x * 128;

    f32x4 acc[4][4];
    #pragma unroll
    for (int i = 0; i < 4; ++i)
        #pragma unroll
        for (int j = 0; j < 4; ++j)
            #pragma unroll
            for (int r = 0; r < 4; ++r) acc[i][j][r] = 0.f;

    gemm_mainloop(A, W, m0, n0, DIMN, As, Bs, acc);

    #pragma unroll
    for (int mt = 0; mt < 4; ++mt) {
        #pragma unroll
        for (int nt = 0; nt < 4; ++nt) {
            const int n = n0 + wn * 64 + nt * 16 + col;
            const float bb = bias[n];
            #pragma unroll
            for (int r = 0; r < 4; ++r) {
                const int m = m0 + wm * 64 + mt * 16 + quad * 4 + r;
                Yf[(size_t)m * DIMN + n] = acc[mt][nt][r] + bb;
            }
        }
    }
}

// ---------------------------------------------------------------------------
// Fused RMSNorm + RoPE for Q (grid.y==0, in-place) and K->Kp (grid.y==1).
// ---------------------------------------------------------------------------
__global__ __launch_bounds__(256)
void rms_rope_qk(short* __restrict__ qbuf, const short* __restrict__ kbuf,
                 short* __restrict__ Kp,
                 const float* __restrict__ gq, const float* __restrict__ gk,
                 const float* __restrict__ freqs, const int* __restrict__ grid_sizes)
{
    const int s = blockIdx.x;
    const int isK = blockIdx.y;
    const int tid = threadIdx.x;
    short* qrow = qbuf + (size_t)s * DIMN;
    const short* row = isK ? (kbuf + (size_t)s * DIMN) : qrow;
    const float* g = isK ? gk : gq;

    float ss = 0.f;
    if (tid < 192) {
        short8 v = *(const short8*)(row + tid * 8);
        #pragma unroll
        for (int j = 0; j < 8; ++j) { float f = bf_to_f(v[j]); ss += f * f; }
    }
    #pragma unroll
    for (int off = 32; off; off >>= 1) ss += __shfl_down(ss, off, 64);

    __shared__ float red[4];
    __shared__ float s_scale;
    if ((tid & 63) == 0) red[tid >> 6] = ss;
    __syncthreads();
    if (tid == 0) {
        float t = red[0] + red[1] + red[2] + red[3];
        float sc = rsqrtf(t / (float)DIMN + EPSV);
        s_scale = isK ? sc : sc * 0.08838834764831845f;
    }
    __syncthreads();
    const float scale = s_scale;

    const int h = grid_sizes[1], w = grid_sizes[2];
    const int fi = s / (h * w);
    const int hi = (s / w) % h;
    const int wi = s % w;

    if (!isK) {
        for (int p = tid; p < NHEAD * 64; p += 256) {
            const int n = p >> 6;
            const int d = p & 63;
            const int idx = (d < 22) ? fi : ((d < 43) ? hi : wi);
            const float ang = freqs[idx * 64 + d];
            float sn, cs;
            __sincosf(ang, &sn, &cs);
            const int base = n * HDIM + 2 * d;
            const float v0 = bf_to_f(qrow[base]) * scale * g[base];
            const float v1 = bf_to_f(qrow[base + 1]) * scale * g[base + 1];
            qrow[base]     = to_bf16(v0 * cs - v1 * sn);
            qrow[base + 1] = to_bf16(v0 * sn + v1 * cs);
        }
    } else if (tid < 192) {
        const int n = tid >> 4;
        const int o = tid & 15;
        short8 outv;
        #pragma unroll
        for (int pp = 0; pp < 4; ++pp) {
            const int pd = o * 4 + pp;
            const int idx = (pd < 22) ? fi : ((pd < 43) ? hi : wi);
            const float ang = freqs[idx * 64 + pd];
            float sn, cs;
            __sincosf(ang, &sn, &cs);
            const int base = n * HDIM + 2 * pd;
            const float v0 = bf_to_f(row[base]) * scale * g[base];
            const float v1 = bf_to_f(row[base + 1]) * scale * g[base + 1];
            outv[pp * 2]     = to_bf16(v0 * cs - v1 * sn);
            outv[pp * 2 + 1] = to_bf16(v0 * sn + v1 * cs);
        }
        const int kb = s >> 4, colk = s & 15;
        const int kc = o >> 2, quadk = o & 3;
        const size_t addr = ((((size_t)(n * 128 + kb) * 4 + kc) * 64) + quadk * 16 + colk) * 8;
        *(short8*)(Kp + addr) = outv;
    }
}

// ---------------------------------------------------------------------------
// MFMA flash attention v10 — 32 q-rows/wave + in-block split-K.
//
// Post-mortem: v8 (3 waves/CU) and v9 (12 waves/CU) have IDENTICAL per-wave
// byte-rates (~8 GB/s): waves don't fill each other's stalls because at high
// occupancy aggregate L2 demand (~25 TB/s, 72% of ceiling) inflates load
// latency — TLP and queueing cancel. Lever: arithmetic intensity. Each wave
// now owns 32 q-rows (2 row-tiles) so each 16 KB K/V step feeds 32 MFMA
// (2x v9), halving total L2 traffic to 786 MB. Split-K=2 stays INSIDE a
// 2-wave block (wave0 keys 0..1023, wave1 keys 1024..2047, same rows;
// LDS combine at the end) -> 768 balanced blocks, 6 waves/CU, no global
// combine, no per-step barriers. K for step+1 prefetched into a ping-pong
// register pair under exp+PV. VGPR ~240.
// ---------------------------------------------------------------------------
__global__ __launch_bounds__(128)
void attn_mfma10(const short* __restrict__ Q, const short* __restrict__ Kp,
                 const short* __restrict__ Vp, short* __restrict__ O,
                 const int* __restrict__ seq_lens)
{
    __shared__ __attribute__((aligned(16))) short psw[2 * 1280]; // P transpose, per wave
    __shared__ __attribute__((aligned(16))) float sacc[32 * 132]; // combine: 32 rows x 128d
    __shared__ float sl[32];                                      // combine: row sums

    const int tid  = threadIdx.x;
    const int wave = tid >> 6;           // 0: keys 0..1023, 1: keys 1024..2047
    const int lane = tid & 63;
    const int quad = lane >> 4, col = lane & 15;

    // XCD-clustering swizzle: 768 blocks -> 8 chunks of 96 (1.5 heads of
    // K/V ~ 1.5 MB per XCD L2). Bijective since 768 % 8 == 0.
    const int orig = blockIdx.y * 64 + blockIdx.x;
    const int work = (orig & 7) * 96 + (orig >> 3);
    const int head = work >> 6;
    const int row0 = (work & 63) * 32;
    const int slen = seq_lens[0];

    // Q fragments: 2 row-tiles x 4 k-chunks.
    short8 qf[2][4];
    #pragma unroll
    for (int T = 0; T < 2; ++T)
        #pragma unroll
        for (int kc = 0; kc < 4; ++kc)
            qf[T][kc] = *(const short8*)(Q + (size_t)(row0 + T * 16 + col) * DIMN
                                         + head * HDIM + kc * 32 + quad * 8);

    f32x4 oacc[2][8];
    #pragma unroll
    for (int T = 0; T < 2; ++T)
        #pragma unroll
        for (int dt = 0; dt < 8; ++dt)
            #pragma unroll
            for (int r = 0; r < 4; ++r) oacc[T][dt][r] = 0.f;
    float lsum[2][4];
    #pragma unroll
    for (int T = 0; T < 2; ++T)
        #pragma unroll
        for (int r = 0; r < 4; ++r) lsum[T][r] = 0.f;

    const short* kbase = Kp + (size_t)head * 262144 + lane * 8;
    const short* vbase = Vp + (size_t)head * 262144 + lane * 8;
    short* pswm = psw + wave * 1280;

    const int step0 = wave * 32;

    auto stepf = [&](short8 (&kf)[8], short8 (&kn)[8], int step) {
        // V loads for this step (in flight through QK^T + softmax).
        const short* vs = vbase + (size_t)step * 4096;
        short8 vf[8];
        #pragma unroll
        for (int c = 0; c < 8; ++c) vf[c] = *(const short8*)(vs + c * 512);

        // ---- S = Q K^T: 2 row-tiles x 32 keys (kf already resident) ----
        f32x4 s[2][2];
        #pragma unroll
        for (int T = 0; T < 2; ++T)
            #pragma unroll
            for (int nt = 0; nt < 2; ++nt)
                #pragma unroll
                for (int r = 0; r < 4; ++r) s[T][nt][r] = 0.f;

        #pragma unroll
        for (int kc = 0; kc < 4; ++kc)
            #pragma unroll
            for (int T = 0; T < 2; ++T) {
                s[T][0] = __builtin_amdgcn_mfma_f32_16x16x32_bf16(qf[T][kc], kf[kc],     s[T][0], 0, 0, 0);
                s[T][1] = __builtin_amdgcn_mfma_f32_16x16x32_bf16(qf[T][kc], kf[4 + kc], s[T][1], 0, 0, 0);
            }

        // ---- prefetch next step's K under softmax+PV ----
        // (last iter reads one step past this wave's range: wave0 -> wave1's
        //  first K tile; wave1 -> next head's K (head 11: into ob region,
        //  still allocated). Value unused.)
        const short* kns = kbase + (size_t)(step + 1) * 4096;
        #pragma unroll
        for (int c = 0; c < 8; ++c) kn[c] = *(const short8*)(kns + c * 512);

        // ---- mask + exp (max-free) + l accum + P transpose via tiny LDS ----
        const int kt0 = step * 32;
        #pragma unroll
        for (int T = 0; T < 2; ++T)
            #pragma unroll
            for (int nt = 0; nt < 2; ++nt) {
                const bool masked = (kt0 + nt * 16 + col >= slen);
                #pragma unroll
                for (int r = 0; r < 4; ++r) {
                    float p = masked ? 0.f : __expf(s[T][nt][r]);
                    lsum[T][r] += p;
                    pswm[T * 640 + (quad * 4 + r) * 40 + nt * 16 + col] = to_bf16(p);
                }
            }

        short8 pf0 = *(const short8*)&pswm[col * 40 + quad * 8];
        short8 pf1 = *(const short8*)&pswm[640 + col * 40 + quad * 8];

        // ---- PV: 8 d-tiles x 2 row-tiles ----
        #pragma unroll
        for (int dt = 0; dt < 8; ++dt) {
            oacc[0][dt] = __builtin_amdgcn_mfma_f32_16x16x32_bf16(pf0, vf[dt], oacc[0][dt], 0, 0, 0);
            oacc[1][dt] = __builtin_amdgcn_mfma_f32_16x16x32_bf16(pf1, vf[dt], oacc[1][dt], 0, 0, 0);
        }
    };

    short8 kfA[8], kfB[8];
    {
        const short* ks = kbase + (size_t)step0 * 4096;
        #pragma unroll
        for (int c = 0; c < 8; ++c) kfA[c] = *(const short8*)(ks + c * 512);
    }

    #pragma unroll 1
    for (int kt = 0; kt < 32; kt += 2) {
        stepf(kfA, kfB, step0 + kt);
        stepf(kfB, kfA, step0 + kt + 1);
    }

    // ---- reduce l over the 16 key-columns (within 16-lane groups) ----
    #pragma unroll
    for (int T = 0; T < 2; ++T)
        #pragma unroll
        for (int r = 0; r < 4; ++r) {
            #pragma unroll
            for (int off = 8; off; off >>= 1)
                lsum[T][r] += __shfl_xor(lsum[T][r], off, 64);
        }

    // ---- combine the two key-halves through LDS ----
    if (wave == 1) {
        #pragma unroll
        for (int T = 0; T < 2; ++T) {
            #pragma unroll
            for (int dt = 0; dt < 8; ++dt)
                #pragma unroll
                for (int r = 0; r < 4; ++r)
                    sacc[(T * 16 + quad * 4 + r) * 132 + dt * 16 + col] = oacc[T][dt][r];
            if (col == 0) {
                #pragma unroll
                for (int r = 0; r < 4; ++r) sl[T * 16 + quad * 4 + r] = lsum[T][r];
            }
        }
    }
    __syncthreads();
    if (wave == 0) {
        #pragma unroll
        for (int T = 0; T < 2; ++T) {
            float inv[4];
            #pragma unroll
            for (int r = 0; r < 4; ++r)
                inv[r] = 1.0f / (lsum[T][r] + sl[T * 16 + quad * 4 + r]);
            #pragma unroll
            for (int dt = 0; dt < 8; ++dt)
                #pragma unroll
                for (int r = 0; r < 4; ++r) {
                    const float o = oacc[T][dt][r]
                                  + sacc[(T * 16 + quad * 4 + r) * 132 + dt * 16 + col];
                    O[(size_t)(row0 + T * 16 + quad * 4 + r) * DIMN
                      + head * HDIM + dt * 16 + col] = to_bf16(o * inv[r]);
                }
        }
    }
}

// ---------------------------------------------------------------------------
extern "C" void kernel_launch(void* const* d_in, const int* in_sizes, int n_in,
                              void* d_out, int out_size, void* d_ws, size_t ws_size,
                              hipStream_t stream)
{
    const float* x     = (const float*)d_in[0];
    const float* freqs = (const float*)d_in[1];
    const float* wq    = (const float*)d_in[2];
    const float* bq    = (const float*)d_in[3];
    const float* wk    = (const float*)d_in[4];
    const float* bk    = (const float*)d_in[5];
    const float* wv    = (const float*)d_in[6];
    const float* bv    = (const float*)d_in[7];
    const float* wo    = (const float*)d_in[8];
    const float* bo    = (const float*)d_in[9];
    const float* gq    = (const float*)d_in[10];
    const float* gk    = (const float*)d_in[11];
    const int* seq_lens   = (const int*)d_in[12];
    const int* grid_sizes = (const int*)d_in[13];
    float* out = (float*)d_out;

    const size_t NX = (size_t)SLEN * DIMN;
    const size_t NW = (size_t)DIMN * DIMN;
    short* xb  = (short*)d_ws;
    short* wqb = xb + NX;
    short* wkb = wqb + NW;
    short* wvb = wkb + NW;
    short* wob = wvb + NW;
    short* qb  = wob + NW;
    short* kb  = qb + NX;
    short* vp  = kb + NX;
    short* kp  = vp + NX;
    short* ob  = kp + NX;

    cast5<<<dim3(1536, 5), 256, 0, stream>>>(x, wq, wk, wv, wo,
                                             xb, wqb, wkb, wvb, wob,
                                             (int)NX, (int)NW);

    gemm_qkv<<<dim3(3 * DIMN / 128, SLEN / 128), 256, 0, stream>>>(
        xb, wqb, wkb, wvb, bq, bk, bv, qb, kb, vp);

    rms_rope_qk<<<dim3(SLEN, 2), 256, 0, stream>>>(qb, kb, kp, gq, gk, freqs, grid_sizes);

    attn_mfma10<<<dim3(64, NHEAD), 128, 0, stream>>>(qb, kp, vp, ob, seq_lens);

    gemm_out<<<dim3(DIMN / 128, SLEN / 128), 256, 0, stream>>>(ob, wob, bo, out);
}

// Round 5
// 260.287 us; speedup vs baseline: 1.0665x; 1.0322x over previous
//
#include <hip/hip_runtime.h>
#include <math.h>

#define DIMN 1536
#define NHEAD 12
#define HDIM 128
#define SLEN 2048
#define EPSV 1e-6f

typedef __attribute__((ext_vector_type(8))) short short8;
typedef __attribute__((ext_vector_type(4))) short short4v;
typedef __attribute__((ext_vector_type(4))) float f32x4;

typedef __attribute__((address_space(1))) const void gvoid_t;
typedef __attribute__((address_space(3))) void lvoid_t;

__device__ __forceinline__ void gload_lds16(const void* g, void* l) {
    __builtin_amdgcn_global_load_lds((gvoid_t*)g, (lvoid_t*)l, 16, 0, 0);
}

__device__ inline short to_bf16(float f) {
    union { float f; unsigned u; } v; v.f = f;
    unsigned r = (v.u + 0x7FFFu + ((v.u >> 16) & 1u)) >> 16;
    return (short)r;
}
__device__ inline float bf_to_f(short h) {
    union { unsigned u; float f; } v;
    v.u = ((unsigned)(unsigned short)h) << 16;
    return v.f;
}

// 8-chunk XOR swizzle for the GEMM LDS tiles.
__device__ __forceinline__ int swz8(int row, int c) {
    return c ^ (row & 7);
}

// ---------------------------------------------------------------------------
// Cast 5 fp32 tensors to bf16 (x + 4 weights), one launch.
// ---------------------------------------------------------------------------
__global__ __launch_bounds__(256)
void cast5(const float* s0, const float* s1, const float* s2,
           const float* s3, const float* s4,
           short* d0, short* d1, short* d2, short* d3, short* d4,
           int n0, int nw)
{
    const float* s; short* d; int n;
    switch (blockIdx.y) {
        case 0: s = s0; d = d0; n = n0; break;
        case 1: s = s1; d = d1; n = nw; break;
        case 2: s = s2; d = d2; n = nw; break;
        case 3: s = s3; d = d3; n = nw; break;
        default: s = s4; d = d4; n = nw; break;
    }
    int idx = (blockIdx.x * 256 + threadIdx.x) * 8;
    if (idx >= n) return;
    float4 a = *(const float4*)(s + idx);
    float4 b = *(const float4*)(s + idx + 4);
    short8 r;
    r[0] = to_bf16(a.x); r[1] = to_bf16(a.y); r[2] = to_bf16(a.z); r[3] = to_bf16(a.w);
    r[4] = to_bf16(b.x); r[5] = to_bf16(b.y); r[6] = to_bf16(b.z); r[7] = to_bf16(b.w);
    *(short8*)(d + idx) = r;
}

// ---------------------------------------------------------------------------
// BK=64 MFMA GEMM core (unchanged).
// ---------------------------------------------------------------------------
__device__ __forceinline__ void gemm_mainloop(const short* __restrict__ A,
    const short* __restrict__ W, int m0, int n0, int K,
    short* As, short* Bs, f32x4 (&acc)[4][4])
{
    const int tid = threadIdx.x;
    const int wave = tid >> 6, lane = tid & 63;
    const int quad = lane >> 4, col = lane & 15;
    const int wm = wave >> 1, wn = wave & 1;
    const int sr = tid >> 3;
    const int sc = tid & 7;

    for (int kt = 0; kt < K; kt += 64) {
        __syncthreads();
        #pragma unroll
        for (int i = 0; i < 4; ++i) {
            const int row = i * 32 + sr;
            const int c = swz8(row, sc);
            gload_lds16(A + (size_t)(m0 + row) * K + kt + c * 8, As + i * 2048 + tid * 8);
        }
        #pragma unroll
        for (int i = 0; i < 4; ++i) {
            const int row = i * 32 + sr;
            const int c = swz8(row, sc);
            gload_lds16(W + (size_t)(n0 + row) * K + kt + c * 8, Bs + i * 2048 + tid * 8);
        }
        __syncthreads();

        #pragma unroll
        for (int kb = 0; kb < 2; ++kb) {
            short8 af[4], bf[4];
            #pragma unroll
            for (int mt = 0; mt < 4; ++mt) {
                const int row = wm * 64 + mt * 16 + col;
                af[mt] = *(const short8*)&As[row * 64 + swz8(row, kb * 4 + quad) * 8];
            }
            #pragma unroll
            for (int nt = 0; nt < 4; ++nt) {
                const int row = wn * 64 + nt * 16 + col;
                bf[nt] = *(const short8*)&Bs[row * 64 + swz8(row, kb * 4 + quad) * 8];
            }
            #pragma unroll
            for (int mt = 0; mt < 4; ++mt)
                #pragma unroll
                for (int nt = 0; nt < 4; ++nt)
                    acc[mt][nt] = __builtin_amdgcn_mfma_f32_16x16x32_bf16(
                        af[mt], bf[nt], acc[mt][nt], 0, 0, 0);
        }
    }
}

// ---------------------------------------------------------------------------
// Fused QKV GEMM; sel==2 (V) writes fragment-swizzled Vp directly.
// Vp chunks are 32-key-step-major: chunk = (head*64 + step)*8 + dt, so each
// step's V tile is 8 KB contiguous and fragment-ready.
// ---------------------------------------------------------------------------
__global__ __launch_bounds__(256)
void gemm_qkv(const short* __restrict__ A,
              const short* __restrict__ W0, const short* __restrict__ W1,
              const short* __restrict__ W2,
              const float* __restrict__ b0, const float* __restrict__ b1,
              const float* __restrict__ b2,
              short* __restrict__ Y0, short* __restrict__ Y1,
              short* __restrict__ Vp)
{
    __shared__ __attribute__((aligned(16))) short As[128 * 64];
    __shared__ __attribute__((aligned(16))) short Bs[128 * 64];

    const int sel = blockIdx.x / (DIMN / 128);
    const int nb  = blockIdx.x % (DIMN / 128);
    const short* W    = (sel == 0) ? W0 : (sel == 1) ? W1 : W2;
    const float* bias = (sel == 0) ? b0 : (sel == 1) ? b1 : b2;

    const int tid = threadIdx.x;
    const int wave = tid >> 6, lane = tid & 63;
    const int quad = lane >> 4, col = lane & 15;
    const int wm = wave >> 1, wn = wave & 1;
    const int m0 = blockIdx.y * 128, n0 = nb * 128;

    f32x4 acc[4][4];
    #pragma unroll
    for (int i = 0; i < 4; ++i)
        #pragma unroll
        for (int j = 0; j < 4; ++j)
            #pragma unroll
            for (int r = 0; r < 4; ++r) acc[i][j][r] = 0.f;

    gemm_mainloop(A, W, m0, n0, DIMN, As, Bs, acc);

    if (sel < 2) {
        short* Y = (sel == 0) ? Y0 : Y1;
        #pragma unroll
        for (int mt = 0; mt < 4; ++mt) {
            #pragma unroll
            for (int nt = 0; nt < 4; ++nt) {
                const int n = n0 + wn * 64 + nt * 16 + col;
                const float bb = bias[n];
                #pragma unroll
                for (int r = 0; r < 4; ++r) {
                    const int m = m0 + wm * 64 + mt * 16 + quad * 4 + r;
                    Y[(size_t)m * DIMN + n] = to_bf16(acc[mt][nt][r] + bb);
                }
            }
        }
    } else {
        const int head = nb;
        const int kt64 = blockIdx.y * 2 + wm;
        #pragma unroll
        for (int mt = 0; mt < 4; ++mt) {
            #pragma unroll
            for (int nt = 0; nt < 4; ++nt) {
                const int n = n0 + wn * 64 + nt * 16 + col;
                const float bb = bias[n];
                const int dt = wn * 4 + nt;
                // 32-key step index = kt64*2 + (mt>>1); 8 dt-chunks contiguous.
                const int chunk = (head * 64 + kt64 * 2 + (mt >> 1)) * 8 + dt;
                const int off = ((mt & 1) * 2 + (quad >> 1)) * 128 + col * 8 + (quad & 1) * 4;
                short4v o;
                #pragma unroll
                for (int r = 0; r < 4; ++r) o[r] = to_bf16(acc[mt][nt][r] + bb);
                *(short4v*)(Vp + (size_t)chunk * 512 + off) = o;
            }
        }
    }
}

// ---------------------------------------------------------------------------
// Output-projection GEMM, fp32 out.
// ---------------------------------------------------------------------------
__global__ __launch_bounds__(256)
void gemm_out(const short* __restrict__ A, const short* __restrict__ W,
              const float* __restrict__ bias, float* __restrict__ Yf)
{
    __shared__ __attribute__((aligned(16))) short As[128 * 64];
    __shared__ __attribute__((aligned(16))) short Bs[128 * 64];

    const int tid = threadIdx.x;
    const int wave = tid >> 6, lane = tid & 63;
    const int quad = lane >> 4, col = lane & 15;
    const int wm = wave >> 1, wn = wave & 1;
    const int m0 = blockIdx.y * 128, n0 = blockIdx.x * 128;

    f32x4 acc[4][4];
    #pragma unroll
    for (int i = 0; i < 4; ++i)
        #pragma unroll
        for (int j = 0; j < 4; ++j)
            #pragma unroll
            for (int r = 0; r < 4; ++r) acc[i][j][r] = 0.f;

    gemm_mainloop(A, W, m0, n0, DIMN, As, Bs, acc);

    #pragma unroll
    for (int mt = 0; mt < 4; ++mt) {
        #pragma unroll
        for (int nt = 0; nt < 4; ++nt) {
            const int n = n0 + wn * 64 + nt * 16 + col;
            const float bb = bias[n];
            #pragma unroll
            for (int r = 0; r < 4; ++r) {
                const int m = m0 + wm * 64 + mt * 16 + quad * 4 + r;
                Yf[(size_t)m * DIMN + n] = acc[mt][nt][r] + bb;
            }
        }
    }
}

// ---------------------------------------------------------------------------
// Fused RMSNorm + RoPE for Q (grid.y==0, in-place) and K->Kp (grid.y==1).
// ---------------------------------------------------------------------------
__global__ __launch_bounds__(256)
void rms_rope_qk(short* __restrict__ qbuf, const short* __restrict__ kbuf,
                 short* __restrict__ Kp,
                 const float* __restrict__ gq, const float* __restrict__ gk,
                 const float* __restrict__ freqs, const int* __restrict__ grid_sizes)
{
    const int s = blockIdx.x;
    const int isK = blockIdx.y;
    const int tid = threadIdx.x;
    short* qrow = qbuf + (size_t)s * DIMN;
    const short* row = isK ? (kbuf + (size_t)s * DIMN) : qrow;
    const float* g = isK ? gk : gq;

    float ss = 0.f;
    if (tid < 192) {
        short8 v = *(const short8*)(row + tid * 8);
        #pragma unroll
        for (int j = 0; j < 8; ++j) { float f = bf_to_f(v[j]); ss += f * f; }
    }
    #pragma unroll
    for (int off = 32; off; off >>= 1) ss += __shfl_down(ss, off, 64);

    __shared__ float red[4];
    __shared__ float s_scale;
    if ((tid & 63) == 0) red[tid >> 6] = ss;
    __syncthreads();
    if (tid == 0) {
        float t = red[0] + red[1] + red[2] + red[3];
        float sc = rsqrtf(t / (float)DIMN + EPSV);
        s_scale = isK ? sc : sc * 0.08838834764831845f;
    }
    __syncthreads();
    const float scale = s_scale;

    const int h = grid_sizes[1], w = grid_sizes[2];
    const int fi = s / (h * w);
    const int hi = (s / w) % h;
    const int wi = s % w;

    if (!isK) {
        for (int p = tid; p < NHEAD * 64; p += 256) {
            const int n = p >> 6;
            const int d = p & 63;
            const int idx = (d < 22) ? fi : ((d < 43) ? hi : wi);
            const float ang = freqs[idx * 64 + d];
            float sn, cs;
            __sincosf(ang, &sn, &cs);
            const int base = n * HDIM + 2 * d;
            const float v0 = bf_to_f(qrow[base]) * scale * g[base];
            const float v1 = bf_to_f(qrow[base + 1]) * scale * g[base + 1];
            qrow[base]     = to_bf16(v0 * cs - v1 * sn);
            qrow[base + 1] = to_bf16(v0 * sn + v1 * cs);
        }
    } else if (tid < 192) {
        const int n = tid >> 4;
        const int o = tid & 15;
        short8 outv;
        #pragma unroll
        for (int pp = 0; pp < 4; ++pp) {
            const int pd = o * 4 + pp;
            const int idx = (pd < 22) ? fi : ((pd < 43) ? hi : wi);
            const float ang = freqs[idx * 64 + pd];
            float sn, cs;
            __sincosf(ang, &sn, &cs);
            const int base = n * HDIM + 2 * pd;
            const float v0 = bf_to_f(row[base]) * scale * g[base];
            const float v1 = bf_to_f(row[base + 1]) * scale * g[base + 1];
            outv[pp * 2]     = to_bf16(v0 * cs - v1 * sn);
            outv[pp * 2 + 1] = to_bf16(v0 * sn + v1 * cs);
        }
        const int kb = s >> 4, colk = s & 15;
        const int kc = o >> 2, quadk = o & 3;
        const size_t addr = ((((size_t)(n * 128 + kb) * 4 + kc) * 64) + quadk * 16 + colk) * 8;
        *(short8*)(Kp + addr) = outv;
    }
}

// ---------------------------------------------------------------------------
// MFMA flash attention v11 — v8 prefetch structure + in-block split-K.
//
// Post-mortem data: v8 (full K+V ping-pong, next step's 16 loads issued
// BEFORE compute of current step) ran 2576 cyc/step; v10 (V loaded at top
// of its own step, K-next mid-step) ran 4710 cyc/step. Same VGPR count,
// same traffic per step: source-level load placement is the lever — the
// full-step-ahead cluster gives loads one entire compute phase of slack.
//
// v11 = v8's exact loop shape (loadKV(B,kt+1); compute(A,kt);
// loadKV(A,kt+2); compute(B,kt+1)) with 32 q-rows/wave AND split-K=2
// inside a 2-wave block (wave0 keys 0..1023, wave1 keys 1024..2047; LDS
// combine at the end). 768 blocks = 6 waves/CU (2x v8's occupancy),
// 32 steps/wave at v8's per-step rate.
// ---------------------------------------------------------------------------
__global__ __launch_bounds__(128)
void attn_mfma11(const short* __restrict__ Q, const short* __restrict__ Kp,
                 const short* __restrict__ Vp, short* __restrict__ O,
                 const int* __restrict__ seq_lens)
{
    __shared__ __attribute__((aligned(16))) short psw[2 * 1280]; // P transpose, per wave
    __shared__ __attribute__((aligned(16))) float sacc[32 * 132]; // combine: 32 rows x 128d
    __shared__ float sl[32];                                      // combine: row sums

    const int tid  = threadIdx.x;
    const int wave = tid >> 6;           // 0: keys 0..1023, 1: keys 1024..2047
    const int lane = tid & 63;
    const int quad = lane >> 4, col = lane & 15;

    // XCD-clustering swizzle: 768 blocks -> 8 chunks of 96 (1.5 heads of
    // K/V ~ 1.5 MB per XCD L2). Bijective since 768 % 8 == 0.
    const int orig = blockIdx.y * 64 + blockIdx.x;
    const int work = (orig & 7) * 96 + (orig >> 3);
    const int head = work >> 6;
    const int row0 = (work & 63) * 32;
    const int slen = seq_lens[0];

    // Q fragments: 2 row-tiles x 4 k-chunks.
    short8 qf[2][4];
    #pragma unroll
    for (int T = 0; T < 2; ++T)
        #pragma unroll
        for (int kc = 0; kc < 4; ++kc)
            qf[T][kc] = *(const short8*)(Q + (size_t)(row0 + T * 16 + col) * DIMN
                                         + head * HDIM + kc * 32 + quad * 8);

    f32x4 oacc[2][8];
    #pragma unroll
    for (int T = 0; T < 2; ++T)
        #pragma unroll
        for (int dt = 0; dt < 8; ++dt)
            #pragma unroll
            for (int r = 0; r < 4; ++r) oacc[T][dt][r] = 0.f;
    float lsum[2][4];
    #pragma unroll
    for (int T = 0; T < 2; ++T)
        #pragma unroll
        for (int r = 0; r < 4; ++r) lsum[T][r] = 0.f;

    const short* kbase = Kp + (size_t)head * 262144 + lane * 8;
    const short* vbase = Vp + (size_t)head * 262144 + lane * 8;
    short* pswm = psw + wave * 1280;
    const int step0 = wave * 32;

    auto loadKV = [&](short8 (&kf)[8], short8 (&vf)[8], int step) {
        const short* ks = kbase + (size_t)step * 4096;
        const short* vs = vbase + (size_t)step * 4096;
        #pragma unroll
        for (int c = 0; c < 8; ++c) kf[c] = *(const short8*)(ks + c * 512);
        #pragma unroll
        for (int c = 0; c < 8; ++c) vf[c] = *(const short8*)(vs + c * 512);
    };

    auto compute = [&](short8 (&kf)[8], short8 (&vf)[8], int step) {
        // ---- S = Q K^T: 2 row-tiles x 32 keys ----
        f32x4 s[2][2];
        #pragma unroll
        for (int T = 0; T < 2; ++T)
            #pragma unroll
            for (int nt = 0; nt < 2; ++nt)
                #pragma unroll
                for (int r = 0; r < 4; ++r) s[T][nt][r] = 0.f;

        #pragma unroll
        for (int kc = 0; kc < 4; ++kc)
            #pragma unroll
            for (int T = 0; T < 2; ++T) {
                s[T][0] = __builtin_amdgcn_mfma_f32_16x16x32_bf16(qf[T][kc], kf[kc],     s[T][0], 0, 0, 0);
                s[T][1] = __builtin_amdgcn_mfma_f32_16x16x32_bf16(qf[T][kc], kf[4 + kc], s[T][1], 0, 0, 0);
            }

        // ---- mask + exp (max-free) + l accum + P transpose via tiny LDS ----
        const int kt0 = step * 32;
        #pragma unroll
        for (int T = 0; T < 2; ++T)
            #pragma unroll
            for (int nt = 0; nt < 2; ++nt) {
                const bool masked = (kt0 + nt * 16 + col >= slen);
                #pragma unroll
                for (int r = 0; r < 4; ++r) {
                    float p = masked ? 0.f : __expf(s[T][nt][r]);
                    lsum[T][r] += p;
                    pswm[T * 640 + (quad * 4 + r) * 40 + nt * 16 + col] = to_bf16(p);
                }
            }

        short8 pf0 = *(const short8*)&pswm[col * 40 + quad * 8];
        short8 pf1 = *(const short8*)&pswm[640 + col * 40 + quad * 8];

        // ---- PV: 8 d-tiles x 2 row-tiles ----
        #pragma unroll
        for (int dt = 0; dt < 8; ++dt) {
            oacc[0][dt] = __builtin_amdgcn_mfma_f32_16x16x32_bf16(pf0, vf[dt], oacc[0][dt], 0, 0, 0);
            oacc[1][dt] = __builtin_amdgcn_mfma_f32_16x16x32_bf16(pf1, vf[dt], oacc[1][dt], 0, 0, 0);
        }
    };

    short8 kA[8], vA[8], kB[8], vB[8];
    loadKV(kA, vA, step0);

    #pragma unroll 1
    for (int kt = 0; kt < 32; kt += 2) {
        loadKV(kB, vB, step0 + kt + 1);   // full next-step cluster BEFORE compute
        compute(kA, vA, step0 + kt);
        loadKV(kA, vA, step0 + kt + 2);   // last iter reads one step past this
                                          // wave's range (next head / ob region,
                                          // allocated; value unused)
        compute(kB, vB, step0 + kt + 1);
    }

    // ---- reduce l over the 16 key-columns (within 16-lane groups) ----
    #pragma unroll
    for (int T = 0; T < 2; ++T)
        #pragma unroll
        for (int r = 0; r < 4; ++r) {
            #pragma unroll
            for (int off = 8; off; off >>= 1)
                lsum[T][r] += __shfl_xor(lsum[T][r], off, 64);
        }

    // ---- combine the two key-halves through LDS ----
    if (wave == 1) {
        #pragma unroll
        for (int T = 0; T < 2; ++T) {
            #pragma unroll
            for (int dt = 0; dt < 8; ++dt)
                #pragma unroll
                for (int r = 0; r < 4; ++r)
                    sacc[(T * 16 + quad * 4 + r) * 132 + dt * 16 + col] = oacc[T][dt][r];
            if (col == 0) {
                #pragma unroll
                for (int r = 0; r < 4; ++r) sl[T * 16 + quad * 4 + r] = lsum[T][r];
            }
        }
    }
    __syncthreads();
    if (wave == 0) {
        #pragma unroll
        for (int T = 0; T < 2; ++T) {
            float inv[4];
            #pragma unroll
            for (int r = 0; r < 4; ++r)
                inv[r] = 1.0f / (lsum[T][r] + sl[T * 16 + quad * 4 + r]);
            #pragma unroll
            for (int dt = 0; dt < 8; ++dt)
                #pragma unroll
                for (int r = 0; r < 4; ++r) {
                    const float o = oacc[T][dt][r]
                                  + sacc[(T * 16 + quad * 4 + r) * 132 + dt * 16 + col];
                    O[(size_t)(row0 + T * 16 + quad * 4 + r) * DIMN
                      + head * HDIM + dt * 16 + col] = to_bf16(o * inv[r]);
                }
        }
    }
}

// ---------------------------------------------------------------------------
extern "C" void kernel_launch(void* const* d_in, const int* in_sizes, int n_in,
                              void* d_out, int out_size, void* d_ws, size_t ws_size,
                              hipStream_t stream)
{
    const float* x     = (const float*)d_in[0];
    const float* freqs = (const float*)d_in[1];
    const float* wq    = (const float*)d_in[2];
    const float* bq    = (const float*)d_in[3];
    const float* wk    = (const float*)d_in[4];
    const float* bk    = (const float*)d_in[5];
    const float* wv    = (const float*)d_in[6];
    const float* bv    = (const float*)d_in[7];
    const float* wo    = (const float*)d_in[8];
    const float* bo    = (const float*)d_in[9];
    const float* gq    = (const float*)d_in[10];
    const float* gk    = (const float*)d_in[11];
    const int* seq_lens   = (const int*)d_in[12];
    const int* grid_sizes = (const int*)d_in[13];
    float* out = (float*)d_out;

    const size_t NX = (size_t)SLEN * DIMN;
    const size_t NW = (size_t)DIMN * DIMN;
    short* xb  = (short*)d_ws;
    short* wqb = xb + NX;
    short* wkb = wqb + NW;
    short* wvb = wkb + NW;
    short* wob = wvb + NW;
    short* qb  = wob + NW;
    short* kb  = qb + NX;
    short* vp  = kb + NX;
    short* kp  = vp + NX;
    short* ob  = kp + NX;

    cast5<<<dim3(1536, 5), 256, 0, stream>>>(x, wq, wk, wv, wo,
                                             xb, wqb, wkb, wvb, wob,
                                             (int)NX, (int)NW);

    gemm_qkv<<<dim3(3 * DIMN / 128, SLEN / 128), 256, 0, stream>>>(
        xb, wqb, wkb, wvb, bq, bk, bv, qb, kb, vp);

    rms_rope_qk<<<dim3(SLEN, 2), 256, 0, stream>>>(qb, kb, kp, gq, gk, freqs, grid_sizes);

    attn_mfma11<<<dim3(64, NHEAD), 128, 0, stream>>>(qb, kp, vp, ob, seq_lens);

    gemm_out<<<dim3(DIMN / 128, SLEN / 128), 256, 0, stream>>>(ob, wob, bo, out);
}